// Round 5
// baseline (850.244 us; speedup 1.0000x reference)
//
#include <hip/hip_runtime.h>
#include <hip/hip_bf16.h>
#include <stdint.h>

// B=256, P=196, ENC=2048, DEC=512, ATT=512. All fp32 on device.
// prep: [0,1024) transpose+cvt W_enc -> W_encT bf16 [512][2048]
//       [1024,1073) zero att; [1073,1329) comb[b][a]=dec·W_dec+b_dec+b_enc
// gemm: 128x128 tile MFMA bf16 (A cvt'd fp32->bf16 packed; B DMA-staged,
//       XOR-swizzled chunks), fused relu+comb+W_full row-reduce -> atomicAdd att
// softmax_ctx: softmax over P, context = alpha-weighted enc sum (fp32)

using u16x8 = __attribute__((ext_vector_type(8))) unsigned short;
using u32x4 = __attribute__((ext_vector_type(4))) unsigned int;
using s16x8 = __attribute__((ext_vector_type(8))) short;
using f32x4 = __attribute__((ext_vector_type(4))) float;

static __device__ __forceinline__ unsigned short f2b(float f) {  // RNE
  unsigned int u = __builtin_bit_cast(unsigned int, f);
  u = u + 0x7fffu + ((u >> 16) & 1u);
  return (unsigned short)(u >> 16);
}
static __device__ __forceinline__ unsigned int cvt_pk(float x, float y) {
  float2 p; p.x = x; p.y = y;
  __hip_bfloat162 h = __float22bfloat162_rn(p);  // v_cvt_pk_bf16_f32 on gfx950
  unsigned int u;
  __builtin_memcpy(&u, &h, 4);  // bit_cast rejected: type not trivially copyable
  return u;
}

// ---------------------------------------------------------------- prep
__global__ __launch_bounds__(256) void prep_kernel(
    const float* __restrict__ wenc, unsigned short* __restrict__ wencT,
    const float* __restrict__ dec, const float* __restrict__ wdec,
    const float* __restrict__ bdec, const float* __restrict__ benc,
    float* __restrict__ comb, float* __restrict__ att) {
  const int bid = blockIdx.x, t = threadIdx.x;
  if (bid < 1024) {  // ---- transpose + cvt
    __shared__ unsigned short tile[32][34];
    const int x = t & 31, y = t >> 5;
    const int kb = bid & 63, nb = bid >> 6;
    const int k0 = kb << 5, n0 = nb << 5;
#pragma unroll
    for (int i = 0; i < 4; ++i) {
      int kk = y * 4 + i;
      tile[x][kk] = f2b(wenc[(size_t)(k0 + kk) * 512 + n0 + x]);
    }
    __syncthreads();
#pragma unroll
    for (int i = 0; i < 4; ++i) {
      int nn = y * 4 + i;
      wencT[(size_t)(n0 + nn) * 2048 + k0 + x] = tile[nn][x];
    }
  } else if (bid < 1073) {  // ---- zero att (49 blocks x 1024 floats)
    int idx = (bid - 1024) * 1024 + t * 4;
    *(f32x4*)&att[idx] = (f32x4){0.f, 0.f, 0.f, 0.f};
  } else {  // ---- comb (256 blocks, one batch each)
    __shared__ float dec_sh[512];
    const int b = bid - 1073;
    dec_sh[t] = dec[(size_t)b * 512 + t];
    dec_sh[256 + t] = dec[(size_t)b * 512 + 256 + t];
    __syncthreads();
    const int a0 = 2 * t;
    float acc0 = bdec[a0] + benc[a0];
    float acc1 = bdec[a0 + 1] + benc[a0 + 1];
    for (int e = 0; e < 512; ++e) {
      float2 wv = *(const float2*)&wdec[(size_t)e * 512 + a0];
      float d = dec_sh[e];
      acc0 = fmaf(d, wv.x, acc0);
      acc1 = fmaf(d, wv.y, acc1);
    }
    float2 o; o.x = acc0; o.y = acc1;
    *(float2*)&comb[(size_t)b * 512 + a0] = o;
  }
}

// ---------------------------------------------------------------- gemm
static __device__ __forceinline__ void load_lds16(const unsigned short* g,
                                                  unsigned short* l) {
  __builtin_amdgcn_global_load_lds(
      (const __attribute__((address_space(1))) unsigned int*)g,
      (__attribute__((address_space(3))) unsigned int*)l, 16, 0, 0);
}

#define LROWA 40  // A LDS pitch (ushorts): conflict-free frag reads

__global__ __launch_bounds__(256, 3) void gemm_att(
    const float* __restrict__ enc, const unsigned short* __restrict__ wencT,
    const float* __restrict__ comb, const float* __restrict__ wfull_g,
    float* __restrict__ att) {
  __shared__ alignas(16) unsigned short Ash[128 * LROWA];  // 10 KB
  __shared__ alignas(16) unsigned short Bsh[128 * 32];     // 8 KB (DMA, swizzled)
  __shared__ float comb_sh[256];
  __shared__ float wfull_sh[128];

  const int t = threadIdx.x;
  const int w = t >> 6, l = t & 63;
  const int quad = l >> 4, col = l & 15;
  const int wm = w >> 1, wn = w & 1;
  const int mb = blockIdx.x >> 2, nb = blockIdx.x & 3;
  const int r0 = mb * 128, n0 = nb * 128;
  const int b0 = r0 / 196;
  const int rsw = (b0 + 1) * 196;
  const int b1 = (b0 + 1 < 256) ? b0 + 1 : 255;

  if (t < 128) {
    comb_sh[t] = comb[(size_t)b0 * 512 + n0 + t];
    wfull_sh[t] = wfull_g[n0 + t];
  } else {
    comb_sh[t] = comb[(size_t)b1 * 512 + n0 + (t - 128)];
  }

  // A staging: thread -> (row m = t>>1, half h = t&1), 16 floats/thread/step
  const float* agp = enc + (size_t)(r0 + (t >> 1)) * 2048 + (t & 1) * 16;
  unsigned short* alp = &Ash[(t >> 1) * LROWA + (t & 1) * 16];

  // B DMA: chunk q -> (n=q>>2, kc_log=(q&3)^((q>>4)&3)); LDS dest contiguous.
  const unsigned short* bgp[2];
  unsigned short* blp[2];
#pragma unroll
  for (int j = 0; j < 2; ++j) {
    int q = (w * 2 + j) * 64 + l;
    int n = q >> 2, kc = (q & 3) ^ ((q >> 4) & 3);
    bgp[j] = wencT + (size_t)(n0 + n) * 2048 + kc * 8;
    blp[j] = &Bsh[(w * 2 + j) * 512];  // wave-uniform base (+lane*16B by HW)
  }

  // frag offsets (ushort units)
  int aoff[4], boff[4];
#pragma unroll
  for (int mt = 0; mt < 4; ++mt)
    aoff[mt] = (wm * 64 + mt * 16 + col) * LROWA + quad * 8;
#pragma unroll
  for (int nt = 0; nt < 4; ++nt) {
    int nl = wn * 64 + nt * 16 + col;
    boff[nt] = nl * 32 + (quad ^ ((nl >> 2) & 3)) * 8;
  }

  f32x4 acc[4][4];
#pragma unroll
  for (int mt = 0; mt < 4; ++mt)
#pragma unroll
    for (int nt = 0; nt < 4; ++nt) acc[mt][nt] = (f32x4){0.f, 0.f, 0.f, 0.f};

  for (int ks = 0; ks < 64; ++ks) {
    // A global loads (overlap prev iter MFMA)
    f32x4 av[4];
#pragma unroll
    for (int i = 0; i < 4; ++i) av[i] = *(const f32x4*)(agp + i * 4);

    __syncthreads();  // prev frag reads done

    // packed cvt + A LDS write
    u32x4 pk0, pk1;
#pragma unroll
    for (int i = 0; i < 2; ++i) {
      pk0[2 * i]     = cvt_pk(av[i][0], av[i][1]);
      pk0[2 * i + 1] = cvt_pk(av[i][2], av[i][3]);
      pk1[2 * i]     = cvt_pk(av[i + 2][0], av[i + 2][1]);
      pk1[2 * i + 1] = cvt_pk(av[i + 2][2], av[i + 2][3]);
    }
    *(u32x4*)alp = pk0;
    *(u32x4*)(alp + 8) = pk1;
    // B DMA
#pragma unroll
    for (int j = 0; j < 2; ++j) load_lds16(bgp[j], blp[j]);

    __syncthreads();  // drains vmcnt+lgkm

    s16x8 afr[4];
#pragma unroll
    for (int mt = 0; mt < 4; ++mt) afr[mt] = *(const s16x8*)&Ash[aoff[mt]];
#pragma unroll
    for (int nt = 0; nt < 4; ++nt) {
      s16x8 bfr = *(const s16x8*)&Bsh[boff[nt]];
#pragma unroll
      for (int mt = 0; mt < 4; ++mt)
        acc[mt][nt] = __builtin_amdgcn_mfma_f32_16x16x32_bf16(afr[mt], bfr, acc[mt][nt], 0, 0, 0);
    }

    agp += 32;
#pragma unroll
    for (int j = 0; j < 2; ++j) bgp[j] += 32;
  }

  // epilogue: relu(C+comb)*wfull, reduce over this block's 128 cols -> att
#pragma unroll
  for (int mt = 0; mt < 4; ++mt) {
#pragma unroll
    for (int r = 0; r < 4; ++r) {
      int rl = wm * 64 + mt * 16 + quad * 4 + r;  // C/D: row=quad*4+reg
      int cb = ((r0 + rl) >= rsw) ? 128 : 0;
      float s = 0.f;
#pragma unroll
      for (int nt = 0; nt < 4; ++nt) {
        int nl = wn * 64 + nt * 16 + col;  // C/D: col=lane&15
        float v = acc[mt][nt][r] + comb_sh[cb + nl];
        v = fmaxf(v, 0.f);
        s = fmaf(v, wfull_sh[nl], s);
      }
      s += __shfl_xor(s, 1);
      s += __shfl_xor(s, 2);
      s += __shfl_xor(s, 4);
      s += __shfl_xor(s, 8);
      if (col == 0) atomicAdd(&att[(size_t)r0 + rl], s);
    }
  }
}

// ---------------------------------------------------------------- softmax+context
__global__ __launch_bounds__(256) void softmax_ctx(
    const float* __restrict__ att, const float* __restrict__ enc,
    float* __restrict__ ctx_out, float* __restrict__ alpha_out) {
  const int b = blockIdx.x, chunk = blockIdx.y, t = threadIdx.x;
  __shared__ float red[256];
  __shared__ float alpha_sh[196];

  float v = (t < 196) ? att[(size_t)b * 196 + t] : -1e30f;
  red[t] = v;
  __syncthreads();
  for (int s = 128; s > 0; s >>= 1) {
    if (t < s) red[t] = fmaxf(red[t], red[t + s]);
    __syncthreads();
  }
  float mx = red[0];
  __syncthreads();
  float e = (t < 196) ? __expf(v - mx) : 0.f;
  red[t] = e;
  __syncthreads();
  for (int s = 128; s > 0; s >>= 1) {
    if (t < s) red[t] += red[t + s];
    __syncthreads();
  }
  float a = e / red[0];
  if (t < 196) {
    alpha_sh[t] = a;
    if (chunk == 0) alpha_out[(size_t)b * 196 + t] = a;
  }
  __syncthreads();

  f32x4 acc = (f32x4){0.f, 0.f, 0.f, 0.f};
  const float* ep = enc + (size_t)b * 196 * 2048 + chunk * 1024 + t * 4;
#pragma unroll 4
  for (int p = 0; p < 196; ++p) {
    float ap = alpha_sh[p];
    f32x4 ev = *(const f32x4*)ep;
    acc[0] = fmaf(ap, ev[0], acc[0]);
    acc[1] = fmaf(ap, ev[1], acc[1]);
    acc[2] = fmaf(ap, ev[2], acc[2]);
    acc[3] = fmaf(ap, ev[3], acc[3]);
    ep += 2048;
  }
  *(f32x4*)&ctx_out[(size_t)b * 2048 + chunk * 1024 + t * 4] = acc;
}

// ---------------------------------------------------------------- launch
extern "C" void kernel_launch(void* const* d_in, const int* in_sizes, int n_in,
                              void* d_out, int out_size, void* d_ws, size_t ws_size,
                              hipStream_t stream) {
  (void)in_sizes; (void)n_in; (void)out_size; (void)ws_size;
  const float* enc   = (const float*)d_in[0];  // [256,196,2048]
  const float* dec   = (const float*)d_in[1];  // [256,512]
  const float* wenc  = (const float*)d_in[2];  // [2048,512]
  const float* benc  = (const float*)d_in[3];  // [512]
  const float* wdec  = (const float*)d_in[4];  // [512,512]
  const float* bdec  = (const float*)d_in[5];  // [512]
  const float* wfull = (const float*)d_in[6];  // [512]
  // d_in[7] (b_full) unused: softmax shift-invariant.

  unsigned short* wencT = (unsigned short*)d_ws;                    // 2 MB
  float* comb = (float*)((char*)d_ws + (2u << 20));                 // 512 KB
  float* att  = (float*)((char*)d_ws + (2u << 20) + (512u << 10));  // 200 KB

  float* ctx_out = (float*)d_out;                    // [256,2048]
  float* alpha_out = ctx_out + (size_t)256 * 2048;   // [256,196]

  hipLaunchKernelGGL(prep_kernel, dim3(1329), dim3(256), 0, stream,
                     wenc, wencT, dec, wdec, bdec, benc, comb, att);
  hipLaunchKernelGGL(gemm_att, dim3(1568), dim3(256), 0, stream,
                     enc, wencT, comb, wfull, att);
  hipLaunchKernelGGL(softmax_ctx, dim3(256, 2), dim3(256), 0, stream,
                     att, enc, ctx_out, alpha_out);
}